// Round 13
// baseline (468.306 us; speedup 1.0000x reference)
//
#include <hip/hip_runtime.h>
#include <hip/hip_bf16.h>
#include <math.h>

#define BB 32
#define SS 512
#define DD 256
#define HH 8
#define HDIM 32
#define FFNN 128
#define NROWS (BB*SS)        // 16384
#define NELEM (NROWS*DD)     // 4194304

using bf16 = __hip_bfloat16;
typedef __attribute__((ext_vector_type(8))) short short8;
typedef __attribute__((ext_vector_type(4))) float floatx4;

static __device__ __forceinline__ float bf2f(bf16 x) { return __bfloat162float(x); }
static __device__ __forceinline__ bf16  f2bf(float x) { return __float2bfloat16(x); }
static __device__ __forceinline__ short f2bfs(float x) {
    bf16 b = __float2bfloat16(x);
    return __builtin_bit_cast(short, b);
}

// async global->LDS, 16B per lane; dest = wave-uniform base + lane*16
static __device__ __forceinline__ void gld_lds16(const void* g, void* l) {
    __builtin_amdgcn_global_load_lds(
        (const __attribute__((address_space(1))) void*)g,
        (__attribute__((address_space(3))) void*)l, 16, 0, 0);
}

// ---------- v dtype probe ----------
__global__ void init_flag(int* flag) { *flag = 0; }
__global__ __launch_bounds__(256) void detect_v(const int* __restrict__ v, int* __restrict__ flag) {
    int i = blockIdx.x * 256 + threadIdx.x;
    if (v[2 * i + 1] != 0) atomicOr(flag, 1);
}

// ---------- one-shot setup: all weight packs (f32 -> bf16 [n][k]) + xPos table ----------
#define NQKVG (3*1024*256)           // 786432
#define NWO   (3*256*256)            // 196608
#define NW1   (3*128*256)            // 98304
#define NW2   (3*256*128)            // 98304
#define NXPT  (512*16)               // 8192
#define NSETUP (NQKVG+NWO+NW1+NW2+NXPT)   // 1187840 = 4640*256
__global__ __launch_bounds__(256) void setup_pack(const float* __restrict__ WQ, const float* __restrict__ WK,
                                                  const float* __restrict__ WV, const float* __restrict__ WG,
                                                  const float* __restrict__ WO, const float* __restrict__ w1,
                                                  const float* __restrict__ w2,
                                                  bf16* __restrict__ dQ, bf16* __restrict__ dO,
                                                  bf16* __restrict__ d1, bf16* __restrict__ d2,
                                                  float4* __restrict__ xpt) {
    int idx = blockIdx.x * 256 + threadIdx.x;
    if (idx < NQKVG) {
        int k = idx & 255, n = (idx >> 8) & 1023, l = idx >> 18;
        int seg = n >> 8, n8 = n & 255;
        float val;
        if (seg < 3) {
            const float* W = (seg == 0) ? WQ : (seg == 1) ? WK : WV;
            int h = n8 >> 5, e = n8 & 31;
            val = W[(((size_t)l * 8 + h) * 256 + k) * 32 + e];
        } else {
            val = WG[(size_t)l * 65536 + k * 256 + n8];
        }
        dQ[((size_t)l * 1024 + n) * 256 + k] = f2bf(val);
    } else if (idx < NQKVG + NWO) {
        int i = idx - NQKVG;
        int k = i & 255, n = (i >> 8) & 255, l = i >> 16;
        dO[((size_t)l * 256 + n) * 256 + k] = f2bf(WO[(size_t)l * 65536 + k * 256 + n]);
    } else if (idx < NQKVG + NWO + NW1) {
        int i = idx - NQKVG - NWO;
        int k = i & 255, n = (i >> 8) & 127, l = i >> 15;
        d1[((size_t)l * 128 + n) * 256 + k] = f2bf(w1[(size_t)l * 32768 + k * 128 + n]);
    } else if (idx < NQKVG + NWO + NW1 + NW2) {
        int i = idx - NQKVG - NWO - NW1;
        int k = i & 127, n = (i >> 7) & 255, l = i >> 15;
        d2[((size_t)l * 256 + n) * 128 + k] = f2bf(w2[(size_t)l * 32768 + k * 256 + n]);
    } else {
        int i = idx - NQKVG - NWO - NW1 - NW2;     // 0..8191
        int jf = i & 15, s = i >> 4;
        float base = (2.0f * jf + 12.8f) / 44.8f;
        float sm = powf(base, (float)s * (1.0f / 512.0f));
        float ang = (float)s * powf(10000.0f, -(float)jf / 16.0f);
        float sn, cs;
        sincosf(ang, &sn, &cs);
        xpt[i] = float4{cs * sm, sn * sm, cs / sm, sn / sm};
    }
}

// ---------- fused embed + LN1(layer0) ----------
__global__ __launch_bounds__(256) void embed_ln_kernel(const int* __restrict__ v,
                                                       const float* __restrict__ emb,
                                                       const int* __restrict__ flag,
                                                       const float* __restrict__ w,
                                                       const float* __restrict__ b,
                                                       float* __restrict__ X,
                                                       short* __restrict__ Xn) {
    int row = blockIdx.x;
    int d = threadIdx.x;
    int tok = (*flag) ? v[row] : v[2 * row];
    float x = 0.0f;
    if (tok != 0) {
        x = emb[tok * DD + d];
        x = x > 0.0f ? x : 0.0f;
    }
    X[(size_t)row * DD + d] = x;
    float s1 = x, s2 = x * x;
    #pragma unroll
    for (int off = 1; off < 64; off <<= 1) {
        s1 += __shfl_xor(s1, off);
        s2 += __shfl_xor(s2, off);
    }
    __shared__ float p1[4], p2[4], st[2];
    int wid = threadIdx.x >> 6;
    if ((threadIdx.x & 63) == 0) { p1[wid] = s1; p2[wid] = s2; }
    __syncthreads();
    if (threadIdx.x == 0) {
        float t1 = p1[0] + p1[1] + p1[2] + p1[3];
        float t2 = p2[0] + p2[1] + p2[2] + p2[3];
        float mu = t1 * (1.0f / DD);
        float var = t2 * (1.0f / DD) - mu * mu;
        st[0] = mu; st[1] = rsqrtf(var + 1e-5f);
    }
    __syncthreads();
    Xn[(size_t)row * DD + d] = f2bfs((x - st[0]) * st[1] * w[d] + b[d]);
}

// ---------- QKVG MFMA GEMM (128x128 tile, XCD-swapped grid) ----------
__global__ __launch_bounds__(256) void qkvg_gemm(const short* __restrict__ A,   // Xn, lda=256
                                                 const short* __restrict__ Bp,  // [1024][256] packed
                                                 const float4* __restrict__ xpt,
                                                 bf16* __restrict__ C) {        // ldc=1024
    __shared__ __align__(16) short Als[16 * 512];
    __shared__ __align__(16) short Bls[16 * 512];
    const int tid = threadIdx.x;
    const int wave = tid >> 6, lane = tid & 63, lo = lane & 15, quad = lane >> 4;
    const int wm = wave >> 1, wn = wave & 1;
    const int row0 = blockIdx.x * 128, col0 = blockIdx.y * 128;

    floatx4 acc[4][4];
    #pragma unroll
    for (int i = 0; i < 4; ++i)
        #pragma unroll
        for (int j = 0; j < 4; ++j) acc[i][j] = floatx4{0.f, 0.f, 0.f, 0.f};

    for (int k0 = 0; k0 < 256; k0 += 64) {
        #pragma unroll
        for (int t = 0; t < 4; ++t) {
            int grp = (wm * 4 + t) * 2 + wn;
            const short* ga = A + (size_t)(row0 + (wm * 4 + t) * 16 + lo) * 256
                            + k0 + (wn * 4 + quad) * 8;
            gld_lds16(ga, &Als[grp * 512]);
        }
        #pragma unroll
        for (int t = 0; t < 4; ++t) {
            int grp = (wn * 4 + t) * 2 + wm;
            const short* gb = Bp + (size_t)(col0 + (wn * 4 + t) * 16 + lo) * 256
                            + k0 + (wm * 4 + quad) * 8;
            gld_lds16(gb, &Bls[grp * 512]);
        }
        __syncthreads();
        #pragma unroll
        for (int kkgrp = 0; kkgrp < 2; ++kkgrp) {
            short8 af[4], bfr[4];
            #pragma unroll
            for (int t = 0; t < 4; ++t)
                af[t] = *(const short8*)(&Als[((wm * 4 + t) * 2 + kkgrp) * 512 + lane * 8]);
            #pragma unroll
            for (int t = 0; t < 4; ++t)
                bfr[t] = *(const short8*)(&Bls[((wn * 4 + t) * 2 + kkgrp) * 512 + lane * 8]);
            #pragma unroll
            for (int ti = 0; ti < 4; ++ti)
                #pragma unroll
                for (int tj = 0; tj < 4; ++tj)
                    acc[ti][tj] = __builtin_amdgcn_mfma_f32_16x16x32_bf16(af[ti], bfr[tj], acc[ti][tj], 0, 0, 0);
        }
        __syncthreads();
    }

    #pragma unroll
    for (int ti = 0; ti < 4; ++ti) {
        #pragma unroll
        for (int tj = 0; tj < 4; ++tj) {
            int colb = col0 + (wn * 4 + tj) * 16 + lo;
            int seg = colb >> 8;
            #pragma unroll
            for (int r = 0; r < 4; ++r) {
                int row = row0 + (wm * 4 + ti) * 16 + quad * 4 + r;
                float v = acc[ti][tj][r];
                if (seg < 2) {
                    int s = row & (SS - 1);
                    int jf = (colb & 31) >> 1;
                    float4 t = xpt[s * 16 + jf];
                    float cs = (seg == 0) ? t.x : t.z;
                    float sn = (seg == 0) ? t.y : t.w;
                    float p = __shfl_xor(v, 1);
                    v = (lo & 1) ? (v * cs + p * sn) : (v * cs - p * sn);
                }
                C[(size_t)row * 1024 + colb] = f2bf(v);
            }
        }
    }
}

// ---------- full-width row GEMM (WO): X += T@WO ; Xn = LN2(X) ----------
__global__ __launch_bounds__(256) void wo_gemm(const short* __restrict__ A,     // T in QKVG, lda=1024
                                               const short* __restrict__ Bp,    // [256][256] packed
                                               float* __restrict__ X,
                                               const float* __restrict__ lnw,
                                               const float* __restrict__ lnb,
                                               short* __restrict__ Out) {
    __shared__ __align__(16) short Als[8 * 512];
    __shared__ __align__(16) short Bls[4][8 * 512];
    __shared__ float Ssum[64][4], Ssq[64][4];
    const int tid = threadIdx.x;
    const int wave = tid >> 6, lane = tid & 63, lo = lane & 15, quad = lane >> 4;
    const int row0 = blockIdx.x * 64;
    const int colw0 = wave * 64;

    floatx4 acc[4][4];
    #pragma unroll
    for (int i = 0; i < 4; ++i)
        #pragma unroll
        for (int j = 0; j < 4; ++j) acc[i][j] = floatx4{0.f, 0.f, 0.f, 0.f};

    const short* Ab = A + (size_t)(row0 + wave * 16 + lo) * 1024 + quad * 8;
    const short* Bb = Bp + (size_t)(colw0 + lo) * 256 + quad * 8;

    for (int k0 = 0; k0 < 256; k0 += 64) {
        gld_lds16(Ab + k0,      &Als[(wave * 2 + 0) * 512]);
        gld_lds16(Ab + k0 + 32, &Als[(wave * 2 + 1) * 512]);
        #pragma unroll
        for (int t = 0; t < 4; ++t)
            #pragma unroll
            for (int kk = 0; kk < 2; ++kk)
                gld_lds16(Bb + (size_t)(t * 16) * 256 + k0 + kk * 32,
                          &Bls[wave][(t * 2 + kk) * 512]);
        __syncthreads();
        #pragma unroll
        for (int kk = 0; kk < 2; ++kk) {
            short8 af[4], bfr[4];
            #pragma unroll
            for (int t = 0; t < 4; ++t)
                af[t] = *(const short8*)(&Als[(t * 2 + kk) * 512 + lane * 8]);
            #pragma unroll
            for (int t = 0; t < 4; ++t)
                bfr[t] = *(const short8*)(&Bls[wave][(t * 2 + kk) * 512 + lane * 8]);
            #pragma unroll
            for (int ti = 0; ti < 4; ++ti)
                #pragma unroll
                for (int tj = 0; tj < 4; ++tj)
                    acc[ti][tj] = __builtin_amdgcn_mfma_f32_16x16x32_bf16(af[ti], bfr[tj], acc[ti][tj], 0, 0, 0);
        }
        __syncthreads();
    }

    float vv[4][4][4];
    #pragma unroll
    for (int ti = 0; ti < 4; ++ti)
        #pragma unroll
        for (int tj = 0; tj < 4; ++tj) {
            int colb = colw0 + tj * 16 + lo;
            #pragma unroll
            for (int r = 0; r < 4; ++r) {
                int row = row0 + ti * 16 + quad * 4 + r;
                float v = acc[ti][tj][r] + X[(size_t)row * DD + colb];
                X[(size_t)row * DD + colb] = v;
                vv[ti][tj][r] = v;
            }
        }
    // row LN
    #pragma unroll
    for (int ti = 0; ti < 4; ++ti)
        #pragma unroll
        for (int r = 0; r < 4; ++r) {
            float s1 = 0.f, s2 = 0.f;
            #pragma unroll
            for (int tj = 0; tj < 4; ++tj) {
                float v = vv[ti][tj][r];
                s1 += v; s2 += v * v;
            }
            #pragma unroll
            for (int off = 1; off < 16; off <<= 1) {
                s1 += __shfl_xor(s1, off);
                s2 += __shfl_xor(s2, off);
            }
            if (lo == 0) {
                int rl = ti * 16 + quad * 4 + r;
                Ssum[rl][wave] = s1;
                Ssq[rl][wave] = s2;
            }
        }
    __syncthreads();
    #pragma unroll
    for (int ti = 0; ti < 4; ++ti)
        #pragma unroll
        for (int r = 0; r < 4; ++r) {
            int rl = ti * 16 + quad * 4 + r;
            float t1 = Ssum[rl][0] + Ssum[rl][1] + Ssum[rl][2] + Ssum[rl][3];
            float t2 = Ssq[rl][0] + Ssq[rl][1] + Ssq[rl][2] + Ssq[rl][3];
            float mu = t1 * (1.0f / DD);
            float var = t2 * (1.0f / DD) - mu * mu;
            float rs = rsqrtf(var + 1e-5f);
            int row = row0 + rl;
            #pragma unroll
            for (int tj = 0; tj < 4; ++tj) {
                int colb = colw0 + tj * 16 + lo;
                Out[(size_t)row * DD + colb] =
                    f2bfs((vv[ti][tj][r] - mu) * rs * lnw[colb] + lnb[colb]);
            }
        }
}

// ---------- fused FFN: Hf = gelu(Xn@w1+b1) in LDS; X += Hf@w2+b2; opt LN -> Xn ----------
#define HSTR 136   // Hf LDS row stride (shorts): 272B -> bank stride 4, 2-way (free)
template<int DOLN>
__global__ __launch_bounds__(256) void ffn_fused(const short* __restrict__ Xn,
                                                 const short* __restrict__ W1p,  // [128][256]
                                                 const float* __restrict__ b1,
                                                 const short* __restrict__ W2p,  // [256][128]
                                                 const float* __restrict__ b2,
                                                 float* __restrict__ X,
                                                 const float* __restrict__ lnw,
                                                 const float* __restrict__ lnb,
                                                 short* __restrict__ Out) {
    __shared__ __align__(16) short Als[8 * 512];        // 8 KB
    __shared__ __align__(16) short Bls[4][8 * 512];     // 32 KB
    __shared__ __align__(16) short Hls[64 * HSTR];      // 17.4 KB
    __shared__ float Ssum[64][4], Ssq[64][4];
    const int tid = threadIdx.x;
    const int wave = tid >> 6, lane = tid & 63, lo = lane & 15, quad = lane >> 4;
    const int row0 = blockIdx.x * 64;

    // ---- phase 1: Hf = gelu(Xn @ w1 + b1), wave owns 32 cols ----
    floatx4 a1[4][2];
    #pragma unroll
    for (int i = 0; i < 4; ++i) { a1[i][0] = floatx4{0,0,0,0}; a1[i][1] = floatx4{0,0,0,0}; }
    const short* Ab = Xn + (size_t)(row0 + wave * 16 + lo) * 256 + quad * 8;
    const short* Bb1 = W1p + (size_t)(wave * 32 + lo) * 256 + quad * 8;
    for (int k0 = 0; k0 < 256; k0 += 64) {
        gld_lds16(Ab + k0,      &Als[(wave * 2 + 0) * 512]);
        gld_lds16(Ab + k0 + 32, &Als[(wave * 2 + 1) * 512]);
        #pragma unroll
        for (int t = 0; t < 2; ++t)
            #pragma unroll
            for (int kk = 0; kk < 2; ++kk)
                gld_lds16(Bb1 + (size_t)(t * 16) * 256 + k0 + kk * 32,
                          &Bls[wave][(t * 2 + kk) * 512]);
        __syncthreads();
        #pragma unroll
        for (int kk = 0; kk < 2; ++kk) {
            short8 af[4], bfr[2];
            #pragma unroll
            for (int t = 0; t < 4; ++t)
                af[t] = *(const short8*)(&Als[(t * 2 + kk) * 512 + lane * 8]);
            #pragma unroll
            for (int t = 0; t < 2; ++t)
                bfr[t] = *(const short8*)(&Bls[wave][(t * 2 + kk) * 512 + lane * 8]);
            #pragma unroll
            for (int ti = 0; ti < 4; ++ti)
                #pragma unroll
                for (int tj = 0; tj < 2; ++tj)
                    a1[ti][tj] = __builtin_amdgcn_mfma_f32_16x16x32_bf16(af[ti], bfr[tj], a1[ti][tj], 0, 0, 0);
        }
        __syncthreads();
    }
    // gelu -> Hls
    #pragma unroll
    for (int ti = 0; ti < 4; ++ti)
        #pragma unroll
        for (int tj = 0; tj < 2; ++tj) {
            int colb = wave * 32 + tj * 16 + lo;
            float bs = b1[colb];
            #pragma unroll
            for (int r = 0; r < 4; ++r) {
                int rl = ti * 16 + quad * 4 + r;
                float v = a1[ti][tj][r] + bs;
                v = 0.5f * v * (1.0f + erff(v * 0.70710678118f));
                Hls[rl * HSTR + colb] = f2bfs(v);
            }
        }

    // ---- phase 2: X += Hf @ w2 + b2, wave owns 64 cols, K=128 ----
    floatx4 a2[4][4];
    #pragma unroll
    for (int i = 0; i < 4; ++i)
        #pragma unroll
        for (int j = 0; j < 4; ++j) a2[i][j] = floatx4{0,0,0,0};
    const short* Bb2 = W2p + (size_t)(wave * 64 + lo) * 128 + quad * 8;
    for (int k0 = 0; k0 < 128; k0 += 64) {
        #pragma unroll
        for (int t = 0; t < 4; ++t)
            #pragma unroll
            for (int kk = 0; kk < 2; ++kk)
                gld_lds16(Bb2 + (size_t)(t * 16) * 128 + k0 + kk * 32,
                          &Bls[wave][(t * 2 + kk) * 512]);
        __syncthreads();   // Hls written (1st iter) + B staged
        #pragma unroll
        for (int kk = 0; kk < 2; ++kk) {
            short8 af[4], bfr[4];
            #pragma unroll
            for (int t = 0; t < 4; ++t)
                af[t] = *(const short8*)(&Hls[(t * 16 + lo) * HSTR + k0 + kk * 32 + quad * 8]);
            #pragma unroll
            for (int t = 0; t < 4; ++t)
                bfr[t] = *(const short8*)(&Bls[wave][(t * 2 + kk) * 512 + lane * 8]);
            #pragma unroll
            for (int ti = 0; ti < 4; ++ti)
                #pragma unroll
                for (int tj = 0; tj < 4; ++tj)
                    a2[ti][tj] = __builtin_amdgcn_mfma_f32_16x16x32_bf16(af[ti], bfr[tj], a2[ti][tj], 0, 0, 0);
        }
        __syncthreads();
    }

    // ---- epilogue ----
    float vv[4][4][4];
    #pragma unroll
    for (int ti = 0; ti < 4; ++ti)
        #pragma unroll
        for (int tj = 0; tj < 4; ++tj) {
            int colb = wave * 64 + tj * 16 + lo;
            float bs = b2[colb];
            #pragma unroll
            for (int r = 0; r < 4; ++r) {
                int row = row0 + ti * 16 + quad * 4 + r;
                float v = a2[ti][tj][r] + bs + X[(size_t)row * DD + colb];
                X[(size_t)row * DD + colb] = v;
                vv[ti][tj][r] = v;
            }
        }
    if (!DOLN) return;
    #pragma unroll
    for (int ti = 0; ti < 4; ++ti)
        #pragma unroll
        for (int r = 0; r < 4; ++r) {
            float s1 = 0.f, s2 = 0.f;
            #pragma unroll
            for (int tj = 0; tj < 4; ++tj) {
                float v = vv[ti][tj][r];
                s1 += v; s2 += v * v;
            }
            #pragma unroll
            for (int off = 1; off < 16; off <<= 1) {
                s1 += __shfl_xor(s1, off);
                s2 += __shfl_xor(s2, off);
            }
            if (lo == 0) {
                int rl = ti * 16 + quad * 4 + r;
                Ssum[rl][wave] = s1;
                Ssq[rl][wave] = s2;
            }
        }
    __syncthreads();
    #pragma unroll
    for (int ti = 0; ti < 4; ++ti)
        #pragma unroll
        for (int r = 0; r < 4; ++r) {
            int rl = ti * 16 + quad * 4 + r;
            float t1 = Ssum[rl][0] + Ssum[rl][1] + Ssum[rl][2] + Ssum[rl][3];
            float t2 = Ssq[rl][0] + Ssq[rl][1] + Ssq[rl][2] + Ssq[rl][3];
            float mu = t1 * (1.0f / DD);
            float var = t2 * (1.0f / DD) - mu * mu;
            float rs = rsqrtf(var + 1e-5f);
            int row = row0 + rl;
            #pragma unroll
            for (int tj = 0; tj < 4; ++tj) {
                int colb = wave * 64 + tj * 16 + lo;
                Out[(size_t)row * DD + colb] =
                    f2bfs((vv[ti][tj][r] - mu) * rs * lnw[colb] + lnb[colb]);
            }
        }
}

// ---------- MFMA retention (32 q-rows/wave) + groupnorm(32) + silu gate ----------
// block swizzle: bh-group-major, qi DESCENDING (long blocks dispatch first -> short tail;
// the 16 blocks of one bh-group adjacent -> shared K/V in L2 per XCD)
#define VSTRIDE 42
__global__ __launch_bounds__(256) void retention_mfma_kernel(bf16* __restrict__ QKVG,
                                                             const float* __restrict__ gnw,
                                                             const float* __restrict__ gnb) {
    __shared__ __align__(16) short Vl[4][32 * VSTRIDE];
    __shared__ __align__(16) short Pl[4][2 * 16 * 40];
    int wslot = threadIdx.x >> 6;
    int lane = threadIdx.x & 63;
    int bhgrp = blockIdx.x >> 4;                  // 0..63
    int qi = 15 - (blockIdx.x & 15);              // 15..0 (long first)
    int bh = (bhgrp << 2) | wslot;
    int b = bh >> 3, h = bh & 7;
    int q0 = qi * 32;
    int lo = lane & 15, quad = lane >> 4;

    const float la0 = -3.46573590280f, la1 = -6.23832462504f;
    float gamma = 1.0f - expf(la0 + (float)h * (la1 - la0) / 7.0f);
    float lg2 = log2f(gamma);

    const size_t base = (size_t)b * SS * 1024;
    const short* QKVGs = (const short*)QKVG;

    short8 qfA = *(const short8*)(QKVGs + base + (size_t)(q0 + lo) * 1024 + h * HDIM + quad * 8);
    short8 qfB = *(const short8*)(QKVGs + base + (size_t)(q0 + 16 + lo) * 1024 + h * HDIM + quad * 8);

    floatx4 oA0 = {0,0,0,0}, oA1 = {0,0,0,0}, oB0 = {0,0,0,0}, oB1 = {0,0,0,0};
    short* Vw = Vl[wslot];
    short* PwA = Pl[wslot];
    short* PwB = Pl[wslot] + 16 * 40;
    int nch = qi + 1;

    for (int ch = 0; ch < nch; ++ch) {
        int t0 = ch * 32;
        const short* Kb = QKVGs + base + 256 + h * HDIM + quad * 8;
        short8 kf0 = *(const short8*)(Kb + (size_t)(t0 + lo) * 1024);
        short8 kf1 = *(const short8*)(Kb + (size_t)(t0 + 16 + lo) * 1024);
        {
            int r = lane >> 2, d = (lane & 3) * 8;
            const uint* Vg1 = (const uint*)(QKVGs + base + (size_t)(t0 + r) * 1024 + 512 + h * HDIM + d);
            const uint* Vg2 = (const uint*)(QKVGs + base + (size_t)(t0 + 16 + r) * 1024 + 512 + h * HDIM + d);
            uint* L1 = (uint*)(Vw + r * VSTRIDE + d);
            uint* L2 = (uint*)(Vw + (16 + r) * VSTRIDE + d);
            #pragma unroll
            for (int w = 0; w < 4; ++w) { L1[w] = Vg1[w]; L2[w] = Vg2[w]; }
        }
        floatx4 z = {0,0,0,0};
        floatx4 sA0 = __builtin_amdgcn_mfma_f32_16x16x32_bf16(qfA, kf0, z, 0, 0, 0);
        floatx4 sA1 = __builtin_amdgcn_mfma_f32_16x16x32_bf16(qfA, kf1, z, 0, 0, 0);
        floatx4 sB0 = __builtin_amdgcn_mfma_f32_16x16x32_bf16(qfB, kf0, z, 0, 0, 0);
        floatx4 sB1 = __builtin_amdgcn_mfma_f32_16x16x32_bf16(qfB, kf1, z, 0, 0, 0);
        #pragma unroll
        for (int r = 0; r < 4; ++r) {
            int qa = q0 + quad * 4 + r;
            int qb = qa + 16;
            int t = t0 + lo;
            float wA0 = (qa >= t)      ? exp2f((float)(qa - t) * lg2)      : 0.0f;
            float wA1 = (qa >= t + 16) ? exp2f((float)(qa - t - 16) * lg2) : 0.0f;
            float wB0 = (qb >= t)      ? exp2f((float)(qb - t) * lg2)      : 0.0f;
            float wB1 = (qb >= t + 16) ? exp2f((float)(qb - t - 16) * lg2) : 0.0f;
            PwA[(quad * 4 + r) * 40 + lo]      = f2bfs(sA0[r] * wA0);
            PwA[(quad * 4 + r) * 40 + 16 + lo] = f2bfs(sA1[r] * wA1);
            PwB[(quad * 4 + r) * 40 + lo]      = f2bfs(sB0[r] * wB0);
            PwB[(quad * 4 + r) * 40 + 16 + lo] = f2bfs(sB1[r] * wB1);
        }
        __syncthreads();
        short8 pfA = *(const short8*)(PwA + lo * 40 + quad * 8);
        short8 pfB = *(const short8*)(PwB + lo * 40 + quad * 8);
        short8 vf0, vf1;
        #pragma unroll
        for (int j = 0; j < 8; ++j) {
            vf0[j] = Vw[(quad * 8 + j) * VSTRIDE + lo];
            vf1[j] = Vw[(quad * 8 + j) * VSTRIDE + 16 + lo];
        }
        oA0 = __builtin_amdgcn_mfma_f32_16x16x32_bf16(pfA, vf0, oA0, 0, 0, 0);
        oA1 = __builtin_amdgcn_mfma_f32_16x16x32_bf16(pfA, vf1, oA1, 0, 0, 0);
        oB0 = __builtin_amdgcn_mfma_f32_16x16x32_bf16(pfB, vf0, oB0, 0, 0, 0);
        oB1 = __builtin_amdgcn_mfma_f32_16x16x32_bf16(pfB, vf1, oB1, 0, 0, 0);
        __syncthreads();
    }

    float gw0 = gnw[h * HDIM + lo], gw1 = gnw[h * HDIM + 16 + lo];
    float gb0 = gnb[h * HDIM + lo], gb1 = gnb[h * HDIM + 16 + lo];
    bf16* QK = QKVG;
    #pragma unroll
    for (int sub = 0; sub < 2; ++sub) {
        floatx4 o0 = sub ? oB0 : oA0;
        floatx4 o1 = sub ? oB1 : oA1;
        int qbase = q0 + sub * 16;
        #pragma unroll
        for (int r = 0; r < 4; ++r) {
            float y0 = o0[r], y1 = o1[r];
            float s = y0 + y1, ss = y0 * y0 + y1 * y1;
            #pragma unroll
            for (int off = 1; off < 16; off <<= 1) {
                s  += __shfl_xor(s, off);
                ss += __shfl_xor(ss, off);
            }
            float mu = s * (1.0f / HDIM);
            float var = ss * (1.0f / HDIM) - mu * mu;
            float rstd = rsqrtf(var + 1e-5f);
            int q = qbase + quad * 4 + r;
            size_t rowb = base + (size_t)q * 1024;
            float g0 = bf2f(QK[rowb + 768 + h * HDIM + lo]);
            float g1 = bf2f(QK[rowb + 768 + h * HDIM + 16 + lo]);
            float t0v = g0 / (1.0f + expf(-g0)) * ((y0 - mu) * rstd * gw0 + gb0);
            float t1v = g1 / (1.0f + expf(-g1)) * ((y1 - mu) * rstd * gw1 + gb1);
            QK[rowb + h * HDIM + lo]      = f2bf(t0v);
            QK[rowb + h * HDIM + 16 + lo] = f2bf(t1v);
        }
    }
}

extern "C" void kernel_launch(void* const* d_in, const int* in_sizes, int n_in,
                              void* d_out, int out_size, void* d_ws, size_t ws_size,
                              hipStream_t stream) {
    const int*   v    = (const int*)d_in[0];
    const float* emb  = (const float*)d_in[1];
    const float* WQ   = (const float*)d_in[2];
    const float* WK   = (const float*)d_in[3];
    const float* WV   = (const float*)d_in[4];
    const float* WG   = (const float*)d_in[5];
    const float* WO   = (const float*)d_in[6];
    const float* gn_w = (const float*)d_in[7];
    const float* gn_b = (const float*)d_in[8];
    const float* ln1w = (const float*)d_in[9];
    const float* ln1b = (const float*)d_in[10];
    const float* ln2w = (const float*)d_in[11];
    const float* ln2b = (const float*)d_in[12];
    const float* w1   = (const float*)d_in[13];
    const float* b1   = (const float*)d_in[14];
    const float* w2   = (const float*)d_in[15];
    const float* b2   = (const float*)d_in[16];

    float* X = (float*)d_out;                    // residual stream (f32) in d_out

    float* base  = (float*)d_ws;
    int*   flag  = (int*)base;
    short* Xn    = (short*)(base + 16);          // NROWS*256 bf16
    bf16*  QKVG  = (bf16*)(Xn + (size_t)NROWS * 256);  // NROWS*1024
    bf16*  WqkvgP = QKVG + (size_t)NROWS * 1024; // 3*1024*256
    bf16*  WoP   = WqkvgP + 3 * 1024 * 256;      // 3*256*256
    bf16*  W1P   = WoP + 3 * 256 * 256;          // 3*128*256
    bf16*  W2P   = W1P + 3 * 128 * 256;          // 3*256*128
    float4* xpt  = (float4*)(W2P + 3 * 256 * 128); // 512*16 float4

    init_flag<<<1, 1, 0, stream>>>(flag);
    detect_v<<<32, 256, 0, stream>>>(v, flag);
    setup_pack<<<NSETUP / 256, 256, 0, stream>>>(WQ, WK, WV, WG, WO, w1, w2,
                                                 WqkvgP, WoP, W1P, W2P, xpt);
    // X = relu(emb[v]); Xn = LN1_0(X)
    embed_ln_kernel<<<NROWS, 256, 0, stream>>>(v, emb, flag, ln1w, ln1b, X, Xn);

    for (int i = 0; i < 3; ++i) {
        // QKVG = xpos(Xn @ [WQ|WK|WV|WG])
        qkvg_gemm<<<dim3(128, 8), 256, 0, stream>>>(Xn,
                                                    (const short*)(WqkvgP + (size_t)i * 1024 * 256),
                                                    xpt, QKVG);
        // retention + gn + gate (T into Q slot)
        retention_mfma_kernel<<<1024, 256, 0, stream>>>(QKVG, gn_w + i * DD, gn_b + i * DD);
        // X += T @ WO ; Xn = LN2(X)
        wo_gemm<<<NROWS / 64, 256, 0, stream>>>((const short*)QKVG,
                                                (const short*)(WoP + (size_t)i * 256 * 256),
                                                X, ln2w + i * DD, ln2b + i * DD, Xn);
        // fused FFN: X += gelu(Xn@w1+b1)@w2 + b2 ; Xn = LN1_{i+1}(X) (skip last)
        if (i < 2)
            ffn_fused<1><<<NROWS / 64, 256, 0, stream>>>(Xn,
                                                         (const short*)(W1P + (size_t)i * 128 * 256),
                                                         b1 + i * FFNN,
                                                         (const short*)(W2P + (size_t)i * 256 * 128),
                                                         b2 + i * DD, X,
                                                         ln1w + (i + 1) * DD, ln1b + (i + 1) * DD, Xn);
        else
            ffn_fused<0><<<NROWS / 64, 256, 0, stream>>>(Xn,
                                                         (const short*)(W1P + (size_t)i * 128 * 256),
                                                         b1 + i * FFNN,
                                                         (const short*)(W2P + (size_t)i * 256 * 128),
                                                         b2 + i * DD, X,
                                                         nullptr, nullptr, nullptr);
    }
}

// Round 14
// 411.528 us; speedup vs baseline: 1.1380x; 1.1380x over previous
//
#include <hip/hip_runtime.h>
#include <hip/hip_bf16.h>
#include <math.h>

#define BB 32
#define SS 512
#define DD 256
#define HH 8
#define HDIM 32
#define FFNN 128
#define NROWS (BB*SS)        // 16384
#define NELEM (NROWS*DD)     // 4194304

using bf16 = __hip_bfloat16;
typedef __attribute__((ext_vector_type(8))) short short8;
typedef __attribute__((ext_vector_type(4))) float floatx4;

static __device__ __forceinline__ float bf2f(bf16 x) { return __bfloat162float(x); }
static __device__ __forceinline__ bf16  f2bf(float x) { return __float2bfloat16(x); }
static __device__ __forceinline__ short f2bfs(float x) {
    bf16 b = __float2bfloat16(x);
    return __builtin_bit_cast(short, b);
}

// async global->LDS, 16B per lane; dest = wave-uniform base + lane*16
static __device__ __forceinline__ void gld_lds16(const void* g, void* l) {
    __builtin_amdgcn_global_load_lds(
        (const __attribute__((address_space(1))) void*)g,
        (__attribute__((address_space(3))) void*)l, 16, 0, 0);
}

// ---------- v dtype probe ----------
__global__ void init_flag(int* flag) { *flag = 0; }
__global__ __launch_bounds__(256) void detect_v(const int* __restrict__ v, int* __restrict__ flag) {
    int i = blockIdx.x * 256 + threadIdx.x;
    if (v[2 * i + 1] != 0) atomicOr(flag, 1);
}

// ---------- one-shot setup: all weight packs (f32 -> bf16 [n][k]) + xPos table ----------
#define NQKVG (3*1024*256)           // 786432
#define NWO   (3*256*256)            // 196608
#define NW1   (3*128*256)            // 98304
#define NW2   (3*256*128)            // 98304
#define NXPT  (512*16)               // 8192
#define NSETUP (NQKVG+NWO+NW1+NW2+NXPT)   // 1187840 = 4640*256
__global__ __launch_bounds__(256) void setup_pack(const float* __restrict__ WQ, const float* __restrict__ WK,
                                                  const float* __restrict__ WV, const float* __restrict__ WG,
                                                  const float* __restrict__ WO, const float* __restrict__ w1,
                                                  const float* __restrict__ w2,
                                                  bf16* __restrict__ dQ, bf16* __restrict__ dO,
                                                  bf16* __restrict__ d1, bf16* __restrict__ d2,
                                                  float4* __restrict__ xpt) {
    int idx = blockIdx.x * 256 + threadIdx.x;
    if (idx < NQKVG) {
        int k = idx & 255, n = (idx >> 8) & 1023, l = idx >> 18;
        int seg = n >> 8, n8 = n & 255;
        float val;
        if (seg < 3) {
            const float* W = (seg == 0) ? WQ : (seg == 1) ? WK : WV;
            int h = n8 >> 5, e = n8 & 31;
            val = W[(((size_t)l * 8 + h) * 256 + k) * 32 + e];
        } else {
            val = WG[(size_t)l * 65536 + k * 256 + n8];
        }
        dQ[((size_t)l * 1024 + n) * 256 + k] = f2bf(val);
    } else if (idx < NQKVG + NWO) {
        int i = idx - NQKVG;
        int k = i & 255, n = (i >> 8) & 255, l = i >> 16;
        dO[((size_t)l * 256 + n) * 256 + k] = f2bf(WO[(size_t)l * 65536 + k * 256 + n]);
    } else if (idx < NQKVG + NWO + NW1) {
        int i = idx - NQKVG - NWO;
        int k = i & 255, n = (i >> 8) & 127, l = i >> 15;
        d1[((size_t)l * 128 + n) * 256 + k] = f2bf(w1[(size_t)l * 32768 + k * 128 + n]);
    } else if (idx < NQKVG + NWO + NW1 + NW2) {
        int i = idx - NQKVG - NWO - NW1;
        int k = i & 127, n = (i >> 7) & 255, l = i >> 15;
        d2[((size_t)l * 256 + n) * 128 + k] = f2bf(w2[(size_t)l * 32768 + k * 256 + n]);
    } else {
        int i = idx - NQKVG - NWO - NW1 - NW2;     // 0..8191
        int jf = i & 15, s = i >> 4;
        float base = (2.0f * jf + 12.8f) / 44.8f;
        float sm = powf(base, (float)s * (1.0f / 512.0f));
        float ang = (float)s * powf(10000.0f, -(float)jf / 16.0f);
        float sn, cs;
        sincosf(ang, &sn, &cs);
        xpt[i] = float4{cs * sm, sn * sm, cs / sm, sn / sm};
    }
}

// ---------- fused embed + LN1(layer0) ----------
__global__ __launch_bounds__(256) void embed_ln_kernel(const int* __restrict__ v,
                                                       const float* __restrict__ emb,
                                                       const int* __restrict__ flag,
                                                       const float* __restrict__ w,
                                                       const float* __restrict__ b,
                                                       float* __restrict__ X,
                                                       short* __restrict__ Xn) {
    int row = blockIdx.x;
    int d = threadIdx.x;
    int tok = (*flag) ? v[row] : v[2 * row];
    float x = 0.0f;
    if (tok != 0) {
        x = emb[tok * DD + d];
        x = x > 0.0f ? x : 0.0f;
    }
    X[(size_t)row * DD + d] = x;
    float s1 = x, s2 = x * x;
    #pragma unroll
    for (int off = 1; off < 64; off <<= 1) {
        s1 += __shfl_xor(s1, off);
        s2 += __shfl_xor(s2, off);
    }
    __shared__ float p1[4], p2[4], st[2];
    int wid = threadIdx.x >> 6;
    if ((threadIdx.x & 63) == 0) { p1[wid] = s1; p2[wid] = s2; }
    __syncthreads();
    if (threadIdx.x == 0) {
        float t1 = p1[0] + p1[1] + p1[2] + p1[3];
        float t2 = p2[0] + p2[1] + p2[2] + p2[3];
        float mu = t1 * (1.0f / DD);
        float var = t2 * (1.0f / DD) - mu * mu;
        st[0] = mu; st[1] = rsqrtf(var + 1e-5f);
    }
    __syncthreads();
    Xn[(size_t)row * DD + d] = f2bfs((x - st[0]) * st[1] * w[d] + b[d]);
}

// ---------- QKVG MFMA GEMM (128x128 tile, XCD-swapped grid) ----------
__global__ __launch_bounds__(256) void qkvg_gemm(const short* __restrict__ A,   // Xn, lda=256
                                                 const short* __restrict__ Bp,  // [1024][256] packed
                                                 const float4* __restrict__ xpt,
                                                 bf16* __restrict__ C) {        // ldc=1024
    __shared__ __align__(16) short Als[16 * 512];
    __shared__ __align__(16) short Bls[16 * 512];
    const int tid = threadIdx.x;
    const int wave = tid >> 6, lane = tid & 63, lo = lane & 15, quad = lane >> 4;
    const int wm = wave >> 1, wn = wave & 1;
    const int row0 = blockIdx.x * 128, col0 = blockIdx.y * 128;

    floatx4 acc[4][4];
    #pragma unroll
    for (int i = 0; i < 4; ++i)
        #pragma unroll
        for (int j = 0; j < 4; ++j) acc[i][j] = floatx4{0.f, 0.f, 0.f, 0.f};

    for (int k0 = 0; k0 < 256; k0 += 64) {
        #pragma unroll
        for (int t = 0; t < 4; ++t) {
            int grp = (wm * 4 + t) * 2 + wn;
            const short* ga = A + (size_t)(row0 + (wm * 4 + t) * 16 + lo) * 256
                            + k0 + (wn * 4 + quad) * 8;
            gld_lds16(ga, &Als[grp * 512]);
        }
        #pragma unroll
        for (int t = 0; t < 4; ++t) {
            int grp = (wn * 4 + t) * 2 + wm;
            const short* gb = Bp + (size_t)(col0 + (wn * 4 + t) * 16 + lo) * 256
                            + k0 + (wm * 4 + quad) * 8;
            gld_lds16(gb, &Bls[grp * 512]);
        }
        __syncthreads();
        #pragma unroll
        for (int kkgrp = 0; kkgrp < 2; ++kkgrp) {
            short8 af[4], bfr[4];
            #pragma unroll
            for (int t = 0; t < 4; ++t)
                af[t] = *(const short8*)(&Als[((wm * 4 + t) * 2 + kkgrp) * 512 + lane * 8]);
            #pragma unroll
            for (int t = 0; t < 4; ++t)
                bfr[t] = *(const short8*)(&Bls[((wn * 4 + t) * 2 + kkgrp) * 512 + lane * 8]);
            #pragma unroll
            for (int ti = 0; ti < 4; ++ti)
                #pragma unroll
                for (int tj = 0; tj < 4; ++tj)
                    acc[ti][tj] = __builtin_amdgcn_mfma_f32_16x16x32_bf16(af[ti], bfr[tj], acc[ti][tj], 0, 0, 0);
        }
        __syncthreads();
    }

    #pragma unroll
    for (int ti = 0; ti < 4; ++ti) {
        #pragma unroll
        for (int tj = 0; tj < 4; ++tj) {
            int colb = col0 + (wn * 4 + tj) * 16 + lo;
            int seg = colb >> 8;
            #pragma unroll
            for (int r = 0; r < 4; ++r) {
                int row = row0 + (wm * 4 + ti) * 16 + quad * 4 + r;
                float v = acc[ti][tj][r];
                if (seg < 2) {
                    int s = row & (SS - 1);
                    int jf = (colb & 31) >> 1;
                    float4 t = xpt[s * 16 + jf];
                    float cs = (seg == 0) ? t.x : t.z;
                    float sn = (seg == 0) ? t.y : t.w;
                    float p = __shfl_xor(v, 1);
                    v = (lo & 1) ? (v * cs + p * sn) : (v * cs - p * sn);
                }
                C[(size_t)row * 1024 + colb] = f2bf(v);
            }
        }
    }
}

// ---------- full-width row GEMM (WO): X += T@WO ; Xn = LN2(X) ----------
__global__ __launch_bounds__(256) void wo_gemm(const short* __restrict__ A,     // T in QKVG, lda=1024
                                               const short* __restrict__ Bp,    // [256][256] packed
                                               float* __restrict__ X,
                                               const float* __restrict__ lnw,
                                               const float* __restrict__ lnb,
                                               short* __restrict__ Out) {
    __shared__ __align__(16) short Als[8 * 512];
    __shared__ __align__(16) short Bls[4][8 * 512];
    __shared__ float Ssum[64][4], Ssq[64][4];
    const int tid = threadIdx.x;
    const int wave = tid >> 6, lane = tid & 63, lo = lane & 15, quad = lane >> 4;
    const int row0 = blockIdx.x * 64;
    const int colw0 = wave * 64;

    floatx4 acc[4][4];
    #pragma unroll
    for (int i = 0; i < 4; ++i)
        #pragma unroll
        for (int j = 0; j < 4; ++j) acc[i][j] = floatx4{0.f, 0.f, 0.f, 0.f};

    const short* Ab = A + (size_t)(row0 + wave * 16 + lo) * 1024 + quad * 8;
    const short* Bb = Bp + (size_t)(colw0 + lo) * 256 + quad * 8;

    for (int k0 = 0; k0 < 256; k0 += 64) {
        gld_lds16(Ab + k0,      &Als[(wave * 2 + 0) * 512]);
        gld_lds16(Ab + k0 + 32, &Als[(wave * 2 + 1) * 512]);
        #pragma unroll
        for (int t = 0; t < 4; ++t)
            #pragma unroll
            for (int kk = 0; kk < 2; ++kk)
                gld_lds16(Bb + (size_t)(t * 16) * 256 + k0 + kk * 32,
                          &Bls[wave][(t * 2 + kk) * 512]);
        __syncthreads();
        #pragma unroll
        for (int kk = 0; kk < 2; ++kk) {
            short8 af[4], bfr[4];
            #pragma unroll
            for (int t = 0; t < 4; ++t)
                af[t] = *(const short8*)(&Als[(t * 2 + kk) * 512 + lane * 8]);
            #pragma unroll
            for (int t = 0; t < 4; ++t)
                bfr[t] = *(const short8*)(&Bls[wave][(t * 2 + kk) * 512 + lane * 8]);
            #pragma unroll
            for (int ti = 0; ti < 4; ++ti)
                #pragma unroll
                for (int tj = 0; tj < 4; ++tj)
                    acc[ti][tj] = __builtin_amdgcn_mfma_f32_16x16x32_bf16(af[ti], bfr[tj], acc[ti][tj], 0, 0, 0);
        }
        __syncthreads();
    }

    float vv[4][4][4];
    #pragma unroll
    for (int ti = 0; ti < 4; ++ti)
        #pragma unroll
        for (int tj = 0; tj < 4; ++tj) {
            int colb = colw0 + tj * 16 + lo;
            #pragma unroll
            for (int r = 0; r < 4; ++r) {
                int row = row0 + ti * 16 + quad * 4 + r;
                float v = acc[ti][tj][r] + X[(size_t)row * DD + colb];
                X[(size_t)row * DD + colb] = v;
                vv[ti][tj][r] = v;
            }
        }
    // row LN
    #pragma unroll
    for (int ti = 0; ti < 4; ++ti)
        #pragma unroll
        for (int r = 0; r < 4; ++r) {
            float s1 = 0.f, s2 = 0.f;
            #pragma unroll
            for (int tj = 0; tj < 4; ++tj) {
                float v = vv[ti][tj][r];
                s1 += v; s2 += v * v;
            }
            #pragma unroll
            for (int off = 1; off < 16; off <<= 1) {
                s1 += __shfl_xor(s1, off);
                s2 += __shfl_xor(s2, off);
            }
            if (lo == 0) {
                int rl = ti * 16 + quad * 4 + r;
                Ssum[rl][wave] = s1;
                Ssq[rl][wave] = s2;
            }
        }
    __syncthreads();
    #pragma unroll
    for (int ti = 0; ti < 4; ++ti)
        #pragma unroll
        for (int r = 0; r < 4; ++r) {
            int rl = ti * 16 + quad * 4 + r;
            float t1 = Ssum[rl][0] + Ssum[rl][1] + Ssum[rl][2] + Ssum[rl][3];
            float t2 = Ssq[rl][0] + Ssq[rl][1] + Ssq[rl][2] + Ssq[rl][3];
            float mu = t1 * (1.0f / DD);
            float var = t2 * (1.0f / DD) - mu * mu;
            float rs = rsqrtf(var + 1e-5f);
            int row = row0 + rl;
            #pragma unroll
            for (int tj = 0; tj < 4; ++tj) {
                int colb = colw0 + tj * 16 + lo;
                Out[(size_t)row * DD + colb] =
                    f2bfs((vv[ti][tj][r] - mu) * rs * lnw[colb] + lnb[colb]);
            }
        }
}

// ---------- fused FFN: Hf = gelu(Xn@w1+b1) in LDS; X += Hf@w2+b2; opt LN -> Xn ----------
#define HSTR 136   // Hf LDS row stride (shorts): 272B -> bank stride 4, 2-way (free)
template<int DOLN>
__global__ __launch_bounds__(256) void ffn_fused(const short* __restrict__ Xn,
                                                 const short* __restrict__ W1p,  // [128][256]
                                                 const float* __restrict__ b1,
                                                 const short* __restrict__ W2p,  // [256][128]
                                                 const float* __restrict__ b2,
                                                 float* __restrict__ X,
                                                 const float* __restrict__ lnw,
                                                 const float* __restrict__ lnb,
                                                 short* __restrict__ Out) {
    __shared__ __align__(16) short Als[8 * 512];        // 8 KB
    __shared__ __align__(16) short Bls[4][8 * 512];     // 32 KB
    __shared__ __align__(16) short Hls[64 * HSTR];      // 17.4 KB
    __shared__ float Ssum[64][4], Ssq[64][4];
    const int tid = threadIdx.x;
    const int wave = tid >> 6, lane = tid & 63, lo = lane & 15, quad = lane >> 4;
    const int row0 = blockIdx.x * 64;

    // ---- phase 1: Hf = gelu(Xn @ w1 + b1), wave owns 32 cols ----
    floatx4 a1[4][2];
    #pragma unroll
    for (int i = 0; i < 4; ++i) { a1[i][0] = floatx4{0,0,0,0}; a1[i][1] = floatx4{0,0,0,0}; }
    const short* Ab = Xn + (size_t)(row0 + wave * 16 + lo) * 256 + quad * 8;
    const short* Bb1 = W1p + (size_t)(wave * 32 + lo) * 256 + quad * 8;
    for (int k0 = 0; k0 < 256; k0 += 64) {
        gld_lds16(Ab + k0,      &Als[(wave * 2 + 0) * 512]);
        gld_lds16(Ab + k0 + 32, &Als[(wave * 2 + 1) * 512]);
        #pragma unroll
        for (int t = 0; t < 2; ++t)
            #pragma unroll
            for (int kk = 0; kk < 2; ++kk)
                gld_lds16(Bb1 + (size_t)(t * 16) * 256 + k0 + kk * 32,
                          &Bls[wave][(t * 2 + kk) * 512]);
        __syncthreads();
        #pragma unroll
        for (int kk = 0; kk < 2; ++kk) {
            short8 af[4], bfr[2];
            #pragma unroll
            for (int t = 0; t < 4; ++t)
                af[t] = *(const short8*)(&Als[(t * 2 + kk) * 512 + lane * 8]);
            #pragma unroll
            for (int t = 0; t < 2; ++t)
                bfr[t] = *(const short8*)(&Bls[wave][(t * 2 + kk) * 512 + lane * 8]);
            #pragma unroll
            for (int ti = 0; ti < 4; ++ti)
                #pragma unroll
                for (int tj = 0; tj < 2; ++tj)
                    a1[ti][tj] = __builtin_amdgcn_mfma_f32_16x16x32_bf16(af[ti], bfr[tj], a1[ti][tj], 0, 0, 0);
        }
        __syncthreads();
    }
    // gelu -> Hls
    #pragma unroll
    for (int ti = 0; ti < 4; ++ti)
        #pragma unroll
        for (int tj = 0; tj < 2; ++tj) {
            int colb = wave * 32 + tj * 16 + lo;
            float bs = b1[colb];
            #pragma unroll
            for (int r = 0; r < 4; ++r) {
                int rl = ti * 16 + quad * 4 + r;
                float v = a1[ti][tj][r] + bs;
                v = 0.5f * v * (1.0f + erff(v * 0.70710678118f));
                Hls[rl * HSTR + colb] = f2bfs(v);
            }
        }

    // ---- phase 2: X += Hf @ w2 + b2, wave owns 64 cols, K=128 ----
    floatx4 a2[4][4];
    #pragma unroll
    for (int i = 0; i < 4; ++i)
        #pragma unroll
        for (int j = 0; j < 4; ++j) a2[i][j] = floatx4{0,0,0,0};
    const short* Bb2 = W2p + (size_t)(wave * 64 + lo) * 128 + quad * 8;
    for (int k0 = 0; k0 < 128; k0 += 64) {
        #pragma unroll
        for (int t = 0; t < 4; ++t)
            #pragma unroll
            for (int kk = 0; kk < 2; ++kk)
                gld_lds16(Bb2 + (size_t)(t * 16) * 128 + k0 + kk * 32,
                          &Bls[wave][(t * 2 + kk) * 512]);
        __syncthreads();   // Hls written (1st iter) + B staged
        #pragma unroll
        for (int kk = 0; kk < 2; ++kk) {
            short8 af[4], bfr[4];
            #pragma unroll
            for (int t = 0; t < 4; ++t)
                af[t] = *(const short8*)(&Hls[(t * 16 + lo) * HSTR + k0 + kk * 32 + quad * 8]);
            #pragma unroll
            for (int t = 0; t < 4; ++t)
                bfr[t] = *(const short8*)(&Bls[wave][(t * 2 + kk) * 512 + lane * 8]);
            #pragma unroll
            for (int ti = 0; ti < 4; ++ti)
                #pragma unroll
                for (int tj = 0; tj < 4; ++tj)
                    a2[ti][tj] = __builtin_amdgcn_mfma_f32_16x16x32_bf16(af[ti], bfr[tj], a2[ti][tj], 0, 0, 0);
        }
        __syncthreads();
    }

    // ---- epilogue ----
    float vv[4][4][4];
    #pragma unroll
    for (int ti = 0; ti < 4; ++ti)
        #pragma unroll
        for (int tj = 0; tj < 4; ++tj) {
            int colb = wave * 64 + tj * 16 + lo;
            float bs = b2[colb];
            #pragma unroll
            for (int r = 0; r < 4; ++r) {
                int row = row0 + ti * 16 + quad * 4 + r;
                float v = a2[ti][tj][r] + bs + X[(size_t)row * DD + colb];
                X[(size_t)row * DD + colb] = v;
                vv[ti][tj][r] = v;
            }
        }
    if (!DOLN) return;
    #pragma unroll
    for (int ti = 0; ti < 4; ++ti)
        #pragma unroll
        for (int r = 0; r < 4; ++r) {
            float s1 = 0.f, s2 = 0.f;
            #pragma unroll
            for (int tj = 0; tj < 4; ++tj) {
                float v = vv[ti][tj][r];
                s1 += v; s2 += v * v;
            }
            #pragma unroll
            for (int off = 1; off < 16; off <<= 1) {
                s1 += __shfl_xor(s1, off);
                s2 += __shfl_xor(s2, off);
            }
            if (lo == 0) {
                int rl = ti * 16 + quad * 4 + r;
                Ssum[rl][wave] = s1;
                Ssq[rl][wave] = s2;
            }
        }
    __syncthreads();
    #pragma unroll
    for (int ti = 0; ti < 4; ++ti)
        #pragma unroll
        for (int r = 0; r < 4; ++r) {
            int rl = ti * 16 + quad * 4 + r;
            float t1 = Ssum[rl][0] + Ssum[rl][1] + Ssum[rl][2] + Ssum[rl][3];
            float t2 = Ssq[rl][0] + Ssq[rl][1] + Ssq[rl][2] + Ssq[rl][3];
            float mu = t1 * (1.0f / DD);
            float var = t2 * (1.0f / DD) - mu * mu;
            float rs = rsqrtf(var + 1e-5f);
            int row = row0 + rl;
            #pragma unroll
            for (int tj = 0; tj < 4; ++tj) {
                int colb = wave * 64 + tj * 16 + lo;
                Out[(size_t)row * DD + colb] =
                    f2bfs((vv[ti][tj][r] - mu) * rs * lnw[colb] + lnb[colb]);
            }
        }
}

// ---------- MFMA retention (32 q-rows/wave) + groupnorm(32) + silu gate ----------
// round-12 dispatch order (qi-major, bh in low bits). Decay via incremental
// multiplicative update: dA[r] = gamma^(qa - t0), *= gamma^-32 per chunk;
// wA0 = wB1 = dA*glo, wA1 = dA*glo*g16i, wB0 = dA*glo*g16p.
#define VSTRIDE 42
__global__ __launch_bounds__(256) void retention_mfma_kernel(bf16* __restrict__ QKVG,
                                                             const float* __restrict__ gnw,
                                                             const float* __restrict__ gnb) {
    __shared__ __align__(16) short Vl[4][32 * VSTRIDE];
    __shared__ __align__(16) short Pl[4][2 * 16 * 40];
    int wslot = threadIdx.x >> 6;
    int lane = threadIdx.x & 63;
    int qi = blockIdx.x >> 6;                     // 0..15 (32-row q-tile), shared by block
    int bh = ((blockIdx.x & 63) << 2) | wslot;
    int b = bh >> 3, h = bh & 7;
    int q0 = qi * 32;
    int lo = lane & 15, quad = lane >> 4;

    const float la0 = -3.46573590280f, la1 = -6.23832462504f;
    float gamma = 1.0f - expf(la0 + (float)h * (la1 - la0) / 7.0f);
    float lg2 = log2f(gamma);
    float glo   = exp2f(-(float)lo * lg2);        // gamma^-lo
    float g16i  = exp2f(-16.0f * lg2);            // gamma^-16
    float g16p  = exp2f(16.0f * lg2);             // gamma^+16
    float gi32  = exp2f(-32.0f * lg2);            // gamma^-32

    const size_t base = (size_t)b * SS * 1024;
    const short* QKVGs = (const short*)QKVG;

    short8 qfA = *(const short8*)(QKVGs + base + (size_t)(q0 + lo) * 1024 + h * HDIM + quad * 8);
    short8 qfB = *(const short8*)(QKVGs + base + (size_t)(q0 + 16 + lo) * 1024 + h * HDIM + quad * 8);

    float dA[4];
    #pragma unroll
    for (int r = 0; r < 4; ++r)
        dA[r] = exp2f((float)(q0 + quad * 4 + r) * lg2);   // gamma^(qa - t0), t0=0

    floatx4 oA0 = {0,0,0,0}, oA1 = {0,0,0,0}, oB0 = {0,0,0,0}, oB1 = {0,0,0,0};
    short* Vw = Vl[wslot];
    short* PwA = Pl[wslot];
    short* PwB = Pl[wslot] + 16 * 40;
    int nch = qi + 1;

    for (int ch = 0; ch < nch; ++ch) {
        int t0 = ch * 32;
        const short* Kb = QKVGs + base + 256 + h * HDIM + quad * 8;
        short8 kf0 = *(const short8*)(Kb + (size_t)(t0 + lo) * 1024);
        short8 kf1 = *(const short8*)(Kb + (size_t)(t0 + 16 + lo) * 1024);
        {
            int r = lane >> 2, d = (lane & 3) * 8;
            const uint* Vg1 = (const uint*)(QKVGs + base + (size_t)(t0 + r) * 1024 + 512 + h * HDIM + d);
            const uint* Vg2 = (const uint*)(QKVGs + base + (size_t)(t0 + 16 + r) * 1024 + 512 + h * HDIM + d);
            uint* L1 = (uint*)(Vw + r * VSTRIDE + d);
            uint* L2 = (uint*)(Vw + (16 + r) * VSTRIDE + d);
            #pragma unroll
            for (int w = 0; w < 4; ++w) { L1[w] = Vg1[w]; L2[w] = Vg2[w]; }
        }
        floatx4 z = {0,0,0,0};
        floatx4 sA0 = __builtin_amdgcn_mfma_f32_16x16x32_bf16(qfA, kf0, z, 0, 0, 0);
        floatx4 sA1 = __builtin_amdgcn_mfma_f32_16x16x32_bf16(qfA, kf1, z, 0, 0, 0);
        floatx4 sB0 = __builtin_amdgcn_mfma_f32_16x16x32_bf16(qfB, kf0, z, 0, 0, 0);
        floatx4 sB1 = __builtin_amdgcn_mfma_f32_16x16x32_bf16(qfB, kf1, z, 0, 0, 0);
        #pragma unroll
        for (int r = 0; r < 4; ++r) {
            int qa = q0 + quad * 4 + r;
            int t = t0 + lo;
            float m = dA[r] * glo;                 // gamma^(qa - t), unmasked
            float wA0 = (qa >= t)      ? m        : 0.0f;
            float wA1 = (qa >= t + 16) ? m * g16i : 0.0f;
            float wB0 = (qa + 16 >= t) ? m * g16p : 0.0f;
            // wB1 == wA0 (same exponent and same mask)
            PwA[(quad * 4 + r) * 40 + lo]      = f2bfs(sA0[r] * wA0);
            PwA[(quad * 4 + r) * 40 + 16 + lo] = f2bfs(sA1[r] * wA1);
            PwB[(quad * 4 + r) * 40 + lo]      = f2bfs(sB0[r] * wB0);
            PwB[(quad * 4 + r) * 40 + 16 + lo] = f2bfs(sB1[r] * wA0);
            dA[r] *= gi32;
        }
        __syncthreads();
        short8 pfA = *(const short8*)(PwA + lo * 40 + quad * 8);
        short8 pfB = *(const short8*)(PwB + lo * 40 + quad * 8);
        short8 vf0, vf1;
        #pragma unroll
        for (int j = 0; j < 8; ++j) {
            vf0[j] = Vw[(quad * 8 + j) * VSTRIDE + lo];
            vf1[j] = Vw[(quad * 8 + j) * VSTRIDE + 16 + lo];
        }
        oA0 = __builtin_amdgcn_mfma_f32_16x16x32_bf16(pfA, vf0, oA0, 0, 0, 0);
        oA1 = __builtin_amdgcn_mfma_f32_16x16x32_bf16(pfA, vf1, oA1, 0, 0, 0);
        oB0 = __builtin_amdgcn_mfma_f32_16x16x32_bf16(pfB, vf0, oB0, 0, 0, 0);
        oB1 = __builtin_amdgcn_mfma_f32_16x16x32_bf16(pfB, vf1, oB1, 0, 0, 0);
        __syncthreads();
    }

    float gw0 = gnw[h * HDIM + lo], gw1 = gnw[h * HDIM + 16 + lo];
    float gb0 = gnb[h * HDIM + lo], gb1 = gnb[h * HDIM + 16 + lo];
    bf16* QK = QKVG;
    #pragma unroll
    for (int sub = 0; sub < 2; ++sub) {
        floatx4 o0 = sub ? oB0 : oA0;
        floatx4 o1 = sub ? oB1 : oA1;
        int qbase = q0 + sub * 16;
        #pragma unroll
        for (int r = 0; r < 4; ++r) {
            float y0 = o0[r], y1 = o1[r];
            float s = y0 + y1, ss = y0 * y0 + y1 * y1;
            #pragma unroll
            for (int off = 1; off < 16; off <<= 1) {
                s  += __shfl_xor(s, off);
                ss += __shfl_xor(ss, off);
            }
            float mu = s * (1.0f / HDIM);
            float var = ss * (1.0f / HDIM) - mu * mu;
            float rstd = rsqrtf(var + 1e-5f);
            int q = qbase + quad * 4 + r;
            size_t rowb = base + (size_t)q * 1024;
            float g0 = bf2f(QK[rowb + 768 + h * HDIM + lo]);
            float g1 = bf2f(QK[rowb + 768 + h * HDIM + 16 + lo]);
            float t0v = g0 / (1.0f + expf(-g0)) * ((y0 - mu) * rstd * gw0 + gb0);
            float t1v = g1 / (1.0f + expf(-g1)) * ((y1 - mu) * rstd * gw1 + gb1);
            QK[rowb + h * HDIM + lo]      = f2bf(t0v);
            QK[rowb + h * HDIM + 16 + lo] = f2bf(t1v);
        }
    }
}

extern "C" void kernel_launch(void* const* d_in, const int* in_sizes, int n_in,
                              void* d_out, int out_size, void* d_ws, size_t ws_size,
                              hipStream_t stream) {
    const int*   v    = (const int*)d_in[0];
    const float* emb  = (const float*)d_in[1];
    const float* WQ   = (const float*)d_in[2];
    const float* WK   = (const float*)d_in[3];
    const float* WV   = (const float*)d_in[4];
    const float* WG   = (const float*)d_in[5];
    const float* WO   = (const float*)d_in[6];
    const float* gn_w = (const float*)d_in[7];
    const float* gn_b = (const float*)d_in[8];
    const float* ln1w = (const float*)d_in[9];
    const float* ln1b = (const float*)d_in[10];
    const float* ln2w = (const float*)d_in[11];
    const float* ln2b = (const float*)d_in[12];
    const float* w1   = (const float*)d_in[13];
    const float* b1   = (const float*)d_in[14];
    const float* w2   = (const float*)d_in[15];
    const float* b2   = (const float*)d_in[16];

    float* X = (float*)d_out;                    // residual stream (f32) in d_out

    float* base  = (float*)d_ws;
    int*   flag  = (int*)base;
    short* Xn    = (short*)(base + 16);          // NROWS*256 bf16
    bf16*  QKVG  = (bf16*)(Xn + (size_t)NROWS * 256);  // NROWS*1024
    bf16*  WqkvgP = QKVG + (size_t)NROWS * 1024; // 3*1024*256
    bf16*  WoP   = WqkvgP + 3 * 1024 * 256;      // 3*256*256
    bf16*  W1P   = WoP + 3 * 256 * 256;          // 3*128*256
    bf16*  W2P   = W1P + 3 * 128 * 256;          // 3*256*128
    float4* xpt  = (float4*)(W2P + 3 * 256 * 128); // 512*16 float4

    init_flag<<<1, 1, 0, stream>>>(flag);
    detect_v<<<32, 256, 0, stream>>>(v, flag);
    setup_pack<<<NSETUP / 256, 256, 0, stream>>>(WQ, WK, WV, WG, WO, w1, w2,
                                                 WqkvgP, WoP, W1P, W2P, xpt);
    // X = relu(emb[v]); Xn = LN1_0(X)
    embed_ln_kernel<<<NROWS, 256, 0, stream>>>(v, emb, flag, ln1w, ln1b, X, Xn);

    for (int i = 0; i < 3; ++i) {
        // QKVG = xpos(Xn @ [WQ|WK|WV|WG])
        qkvg_gemm<<<dim3(128, 8), 256, 0, stream>>>(Xn,
                                                    (const short*)(WqkvgP + (size_t)i * 1024 * 256),
                                                    xpt, QKVG);
        // retention + gn + gate (T into Q slot)
        retention_mfma_kernel<<<1024, 256, 0, stream>>>(QKVG, gn_w + i * DD, gn_b + i * DD);
        // X += T @ WO ; Xn = LN2(X)
        wo_gemm<<<NROWS / 64, 256, 0, stream>>>((const short*)QKVG,
                                                (const short*)(WoP + (size_t)i * 256 * 256),
                                                X, ln2w + i * DD, ln2b + i * DD, Xn);
        // fused FFN: X += gelu(Xn@w1+b1)@w2 + b2 ; Xn = LN1_{i+1}(X) (skip last)
        if (i < 2)
            ffn_fused<1><<<NROWS / 64, 256, 0, stream>>>(Xn,
                                                         (const short*)(W1P + (size_t)i * 128 * 256),
                                                         b1 + i * FFNN,
                                                         (const short*)(W2P + (size_t)i * 256 * 128),
                                                         b2 + i * DD, X,
                                                         ln1w + (i + 1) * DD, ln1b + (i + 1) * DD, Xn);
        else
            ffn_fused<0><<<NROWS / 64, 256, 0, stream>>>(Xn,
                                                         (const short*)(W1P + (size_t)i * 128 * 256),
                                                         b1 + i * FFNN,
                                                         (const short*)(W2P + (size_t)i * 256 * 128),
                                                         b2 + i * DD, X,
                                                         nullptr, nullptr, nullptr);
    }
}